// Round 1
// baseline (1677.105 us; speedup 1.0000x reference)
//
#include <hip/hip_runtime.h>
#include <math.h>

// CapsNet dynamic routing, fp32.
// x: [B=64, N=1152, Din=8], W: [C=128, N=1152, Din=8, Dout=16]
// out: [B=64, C=128, Dout=16]  (normalized per batch at the end)

constexpr int NCAP = 1152;
constexpr int DIN  = 8;
constexpr int DOUT = 16;
constexpr int NCLS = 128;
constexpr int NB   = 64;

constexpr int BLK   = 384;          // 6 waves
constexpr int NWAVE = BLK / 64;
constexpr int NPT   = NCAP / BLK;   // 3 capsules per thread
constexpr int BT    = 2;            // batches per block (W reuse)
constexpr int ITERS = 3;

__global__ __launch_bounds__(BLK) void caps_kernel(const float* __restrict__ x,
                                                   const float* __restrict__ W,
                                                   float* __restrict__ out) {
    const int tid  = threadIdx.x;
    const int lane = tid & 63;
    const int wv   = tid >> 6;

    // XCD-aware mapping: blocks sharing class c land on one XCD so the
    // 576 KB W[c] panel stays L2-resident.  orig&7 ~ XCD id.
    const int orig = blockIdx.x;              // 0..4095
    const int c    = (orig & 7) * 16 + ((orig >> 3) >> 5);   // 0..127
    const int b0   = ((orig >> 3) & 31) * BT;                // 0..62

    __shared__ float lds_vec[NWAVE][BT * DOUT];
    __shared__ float lds_sc[NWAVE][BT];

    // ---- u_hat[c, b0+bt, n, :] for this thread's NPT capsules, in registers
    float u[BT][NPT][DOUT];
#pragma unroll
    for (int bt = 0; bt < BT; ++bt)
#pragma unroll
        for (int k = 0; k < NPT; ++k)
#pragma unroll
            for (int o = 0; o < DOUT; ++o) u[bt][k][o] = 0.0f;

#pragma unroll
    for (int k = 0; k < NPT; ++k) {
        const int n = tid + k * BLK;
        float xs[BT][DIN];
#pragma unroll
        for (int bt = 0; bt < BT; ++bt) {
            const float4* xp = reinterpret_cast<const float4*>(
                x + ((size_t)(b0 + bt) * NCAP + n) * DIN);
            float4 xa = xp[0];
            float4 xb = xp[1];
            float sq = xa.x*xa.x + xa.y*xa.y + xa.z*xa.z + xa.w*xa.w
                     + xb.x*xb.x + xb.y*xb.y + xb.z*xb.z + xb.w*xb.w;
            // squash scale: sq/(1+sq)/sqrt(sq)
            float sc = sq / ((1.0f + sq) * sqrtf(sq));
            xs[bt][0] = xa.x * sc; xs[bt][1] = xa.y * sc;
            xs[bt][2] = xa.z * sc; xs[bt][3] = xa.w * sc;
            xs[bt][4] = xb.x * sc; xs[bt][5] = xb.y * sc;
            xs[bt][6] = xb.z * sc; xs[bt][7] = xb.w * sc;
        }
        const float4* wp = reinterpret_cast<const float4*>(
            W + ((size_t)c * NCAP + n) * (DIN * DOUT));
#pragma unroll
        for (int i = 0; i < DIN; ++i) {
            float4 w0 = wp[i*4+0], w1 = wp[i*4+1], w2 = wp[i*4+2], w3 = wp[i*4+3];
            const float w[DOUT] = {w0.x,w0.y,w0.z,w0.w, w1.x,w1.y,w1.z,w1.w,
                                   w2.x,w2.y,w2.z,w2.w, w3.x,w3.y,w3.z,w3.w};
#pragma unroll
            for (int bt = 0; bt < BT; ++bt) {
                const float xv = xs[bt][i];
#pragma unroll
                for (int o = 0; o < DOUT; ++o)
                    u[bt][k][o] = fmaf(xv, w[o], u[bt][k][o]);
            }
        }
    }

    // ---- dynamic routing, all in registers + tiny LDS reductions
    float brt[BT][NPT];
#pragma unroll
    for (int bt = 0; bt < BT; ++bt)
#pragma unroll
        for (int k = 0; k < NPT; ++k) brt[bt][k] = 0.0f;

    float v[BT][DOUT];

    for (int it = 0; it < ITERS; ++it) {
        // -- block max over N (softmax stability)
        float mx[BT];
#pragma unroll
        for (int bt = 0; bt < BT; ++bt) {
            float m = brt[bt][0];
#pragma unroll
            for (int k = 1; k < NPT; ++k) m = fmaxf(m, brt[bt][k]);
            mx[bt] = m;
        }
#pragma unroll
        for (int off = 1; off < 64; off <<= 1)
#pragma unroll
            for (int bt = 0; bt < BT; ++bt)
                mx[bt] = fmaxf(mx[bt], __shfl_xor(mx[bt], off));
        __syncthreads();
        if (lane == 0)
#pragma unroll
            for (int bt = 0; bt < BT; ++bt) lds_sc[wv][bt] = mx[bt];
        __syncthreads();
#pragma unroll
        for (int bt = 0; bt < BT; ++bt) {
            float m = lds_sc[0][bt];
#pragma unroll
            for (int w2 = 1; w2 < NWAVE; ++w2) m = fmaxf(m, lds_sc[w2][bt]);
            mx[bt] = m;
        }
        // -- exp + block sum
        float e[BT][NPT];
        float sm[BT];
#pragma unroll
        for (int bt = 0; bt < BT; ++bt) {
            float s = 0.0f;
#pragma unroll
            for (int k = 0; k < NPT; ++k) {
                e[bt][k] = __expf(brt[bt][k] - mx[bt]);
                s += e[bt][k];
            }
            sm[bt] = s;
        }
#pragma unroll
        for (int off = 1; off < 64; off <<= 1)
#pragma unroll
            for (int bt = 0; bt < BT; ++bt) sm[bt] += __shfl_xor(sm[bt], off);
        __syncthreads();
        if (lane == 0)
#pragma unroll
            for (int bt = 0; bt < BT; ++bt) lds_sc[wv][bt] = sm[bt];
        __syncthreads();
#pragma unroll
        for (int bt = 0; bt < BT; ++bt) {
            float s = 0.0f;
#pragma unroll
            for (int w2 = 0; w2 < NWAVE; ++w2) s += lds_sc[w2][bt];
            sm[bt] = s;
        }
        // -- s[o] = (sum_n e_n * u[n][o]) / sum_n e_n
        float sp[BT][DOUT];
#pragma unroll
        for (int bt = 0; bt < BT; ++bt)
#pragma unroll
            for (int o = 0; o < DOUT; ++o) sp[bt][o] = 0.0f;
#pragma unroll
        for (int bt = 0; bt < BT; ++bt)
#pragma unroll
            for (int k = 0; k < NPT; ++k) {
                const float ek = e[bt][k];
#pragma unroll
                for (int o = 0; o < DOUT; ++o)
                    sp[bt][o] = fmaf(ek, u[bt][k][o], sp[bt][o]);
            }
#pragma unroll
        for (int off = 1; off < 64; off <<= 1)
#pragma unroll
            for (int bt = 0; bt < BT; ++bt)
#pragma unroll
                for (int o = 0; o < DOUT; ++o)
                    sp[bt][o] += __shfl_xor(sp[bt][o], off);
        __syncthreads();
        if (lane == 0)
#pragma unroll
            for (int bt = 0; bt < BT; ++bt)
#pragma unroll
                for (int o = 0; o < DOUT; ++o) lds_vec[wv][bt*DOUT+o] = sp[bt][o];
        __syncthreads();
#pragma unroll
        for (int bt = 0; bt < BT; ++bt) {
            float sq = 0.0f;
            float sv[DOUT];
#pragma unroll
            for (int o = 0; o < DOUT; ++o) {
                float s = 0.0f;
#pragma unroll
                for (int w2 = 0; w2 < NWAVE; ++w2) s += lds_vec[w2][bt*DOUT+o];
                s /= sm[bt];
                sv[o] = s;
                sq = fmaf(s, s, sq);
            }
            const float scale = sq / ((1.0f + sq) * sqrtf(sq));
#pragma unroll
            for (int o = 0; o < DOUT; ++o) v[bt][o] = sv[o] * scale;
        }
        // -- agreement update (not on last iter)
        if (it < ITERS - 1) {
#pragma unroll
            for (int bt = 0; bt < BT; ++bt)
#pragma unroll
                for (int k = 0; k < NPT; ++k) {
                    float a = 0.0f;
#pragma unroll
                    for (int o = 0; o < DOUT; ++o)
                        a = fmaf(u[bt][k][o], v[bt][o], a);
                    brt[bt][k] += a;
                }
        }
    }

    // ---- leaky_relu(v)^2, write pre-normalized output
    if (tid < BT * DOUT) {
        const int bt = tid >> 4;
        const int o  = tid & 15;
        float val = v[bt][o];
        float l = val > 0.0f ? val : 0.01f * val;
        out[((size_t)(b0 + bt) * NCLS + c) * DOUT + o] = l * l;
    }
}

// per-batch normalization of out[b, :, :] (2048 floats per b), in place
__global__ __launch_bounds__(256) void norm_kernel(float* __restrict__ out) {
    const int b   = blockIdx.x;
    const int tid = threadIdx.x;
    float4* p = reinterpret_cast<float4*>(out + (size_t)b * NCLS * DOUT);
    float4 a0 = p[tid];
    float4 a1 = p[tid + 256];
    float s = a0.x + a0.y + a0.z + a0.w + a1.x + a1.y + a1.z + a1.w;
#pragma unroll
    for (int off = 1; off < 64; off <<= 1) s += __shfl_xor(s, off);
    __shared__ float ws[4];
    if ((tid & 63) == 0) ws[tid >> 6] = s;
    __syncthreads();
    const float inv = 1.0f / (ws[0] + ws[1] + ws[2] + ws[3]);
    a0.x *= inv; a0.y *= inv; a0.z *= inv; a0.w *= inv;
    a1.x *= inv; a1.y *= inv; a1.z *= inv; a1.w *= inv;
    p[tid]       = a0;
    p[tid + 256] = a1;
}

extern "C" void kernel_launch(void* const* d_in, const int* in_sizes, int n_in,
                              void* d_out, int out_size, void* d_ws, size_t ws_size,
                              hipStream_t stream) {
    const float* x = (const float*)d_in[0];
    const float* W = (const float*)d_in[1];
    float* out = (float*)d_out;
    hipLaunchKernelGGL(caps_kernel, dim3(NCLS * (NB / BT)), dim3(BLK), 0, stream,
                       x, W, out);
    hipLaunchKernelGGL(norm_kernel, dim3(NB), dim3(256), 0, stream, out);
}

// Round 2
// 1206.511 us; speedup vs baseline: 1.3900x; 1.3900x over previous
//
#include <hip/hip_runtime.h>
#include <math.h>

// CapsNet dynamic routing, fp32.
// x: [B=64, N=1152, Din=8], W: [C=128, N=1152, Din=8, Dout=16]
// out: [B=64, C=128, Dout=16]  (normalized per batch at the end)
//
// R1 -> R2: BT 2->1. R1 spilled (~4.4 GB scratch traffic, VGPR capped 128,
// occupancy 17%). One (c,b) pair per block keeps all of u_hat (48 regs) +
// routing state under 128 VGPRs with zero spill.

constexpr int NCAP = 1152;
constexpr int DIN  = 8;
constexpr int DOUT = 16;
constexpr int NCLS = 128;
constexpr int NB   = 64;

constexpr int BLK   = 384;          // 6 waves
constexpr int NWAVE = BLK / 64;
constexpr int NPT   = NCAP / BLK;   // 3 capsules per thread
constexpr int ITERS = 3;

__global__ __launch_bounds__(BLK) void caps_kernel(const float* __restrict__ x,
                                                   const float* __restrict__ W,
                                                   float* __restrict__ out) {
    const int tid  = threadIdx.x;
    const int lane = tid & 63;
    const int wv   = tid >> 6;

    // XCD-aware mapping: the 64 blocks sharing class c land on one XCD so the
    // 576 KB W[c] panel stays L2-resident. blockIdx % 8 ~ XCD id.
    const int orig = blockIdx.x;              // 0..8191
    const int xcd  = orig & 7;
    const int rest = orig >> 3;               // 0..1023
    const int c    = xcd * 16 + (rest >> 6);  // 0..127
    const int b    = rest & 63;               // 0..63

    __shared__ float lds_vec[NWAVE][DOUT];
    __shared__ float lds_sc[NWAVE];

    // ---- u_hat[c, b, n, :] for this thread's NPT capsules, in registers
    float u[NPT][DOUT];

#pragma unroll
    for (int k = 0; k < NPT; ++k) {
        const int n = tid + k * BLK;
        // squash(x[b, n, :])
        const float4* xp = reinterpret_cast<const float4*>(
            x + ((size_t)b * NCAP + n) * DIN);
        float4 xa = xp[0];
        float4 xb = xp[1];
        float sq = xa.x*xa.x + xa.y*xa.y + xa.z*xa.z + xa.w*xa.w
                 + xb.x*xb.x + xb.y*xb.y + xb.z*xb.z + xb.w*xb.w;
        float sc = sq / ((1.0f + sq) * sqrtf(sq));
        float xs[DIN] = {xa.x*sc, xa.y*sc, xa.z*sc, xa.w*sc,
                         xb.x*sc, xb.y*sc, xb.z*sc, xb.w*sc};

#pragma unroll
        for (int o = 0; o < DOUT; ++o) u[k][o] = 0.0f;

        const float4* wp = reinterpret_cast<const float4*>(
            W + ((size_t)c * NCAP + n) * (DIN * DOUT));
#pragma unroll
        for (int i = 0; i < DIN; ++i) {
            float4 w0 = wp[i*4+0], w1 = wp[i*4+1], w2 = wp[i*4+2], w3 = wp[i*4+3];
            const float wrow[DOUT] = {w0.x,w0.y,w0.z,w0.w, w1.x,w1.y,w1.z,w1.w,
                                      w2.x,w2.y,w2.z,w2.w, w3.x,w3.y,w3.z,w3.w};
            const float xv = xs[i];
#pragma unroll
            for (int o = 0; o < DOUT; ++o)
                u[k][o] = fmaf(xv, wrow[o], u[k][o]);
        }
    }

    // ---- dynamic routing, all in registers + tiny LDS reductions
    float brt[NPT];
#pragma unroll
    for (int k = 0; k < NPT; ++k) brt[k] = 0.0f;

    float v[DOUT];

    for (int it = 0; it < ITERS; ++it) {
        // -- block max over N (softmax stability)
        float mx = brt[0];
#pragma unroll
        for (int k = 1; k < NPT; ++k) mx = fmaxf(mx, brt[k]);
#pragma unroll
        for (int off = 1; off < 64; off <<= 1)
            mx = fmaxf(mx, __shfl_xor(mx, off));
        __syncthreads();
        if (lane == 0) lds_sc[wv] = mx;
        __syncthreads();
        mx = lds_sc[0];
#pragma unroll
        for (int w2 = 1; w2 < NWAVE; ++w2) mx = fmaxf(mx, lds_sc[w2]);

        // -- exp + block sum
        float e[NPT];
        float sm = 0.0f;
#pragma unroll
        for (int k = 0; k < NPT; ++k) {
            e[k] = __expf(brt[k] - mx);
            sm += e[k];
        }
#pragma unroll
        for (int off = 1; off < 64; off <<= 1) sm += __shfl_xor(sm, off);
        __syncthreads();
        if (lane == 0) lds_sc[wv] = sm;
        __syncthreads();
        sm = 0.0f;
#pragma unroll
        for (int w2 = 0; w2 < NWAVE; ++w2) sm += lds_sc[w2];

        // -- s[o] = (sum_n e_n * u[n][o]) / sum_n e_n, then squash
        float sp[DOUT];
#pragma unroll
        for (int o = 0; o < DOUT; ++o) sp[o] = 0.0f;
#pragma unroll
        for (int k = 0; k < NPT; ++k) {
            const float ek = e[k];
#pragma unroll
            for (int o = 0; o < DOUT; ++o)
                sp[o] = fmaf(ek, u[k][o], sp[o]);
        }
#pragma unroll
        for (int off = 1; off < 64; off <<= 1)
#pragma unroll
            for (int o = 0; o < DOUT; ++o)
                sp[o] += __shfl_xor(sp[o], off);
        __syncthreads();
        if (lane == 0)
#pragma unroll
            for (int o = 0; o < DOUT; ++o) lds_vec[wv][o] = sp[o];
        __syncthreads();
        {
            float sq = 0.0f;
            float sv[DOUT];
#pragma unroll
            for (int o = 0; o < DOUT; ++o) {
                float s = 0.0f;
#pragma unroll
                for (int w2 = 0; w2 < NWAVE; ++w2) s += lds_vec[w2][o];
                s /= sm;
                sv[o] = s;
                sq = fmaf(s, s, sq);
            }
            const float scale = sq / ((1.0f + sq) * sqrtf(sq));
#pragma unroll
            for (int o = 0; o < DOUT; ++o) v[o] = sv[o] * scale;
        }

        // -- agreement update (not on last iter)
        if (it < ITERS - 1) {
#pragma unroll
            for (int k = 0; k < NPT; ++k) {
                float a = 0.0f;
#pragma unroll
                for (int o = 0; o < DOUT; ++o)
                    a = fmaf(u[k][o], v[o], a);
                brt[k] += a;
            }
        }
    }

    // ---- leaky_relu(v)^2, write pre-normalized output
    if (tid < DOUT) {
        const int o = tid;
        float val = v[o];
        float l = val > 0.0f ? val : 0.01f * val;
        out[((size_t)b * NCLS + c) * DOUT + o] = l * l;
    }
}

// per-batch normalization of out[b, :, :] (2048 floats per b), in place
__global__ __launch_bounds__(256) void norm_kernel(float* __restrict__ out) {
    const int b   = blockIdx.x;
    const int tid = threadIdx.x;
    float4* p = reinterpret_cast<float4*>(out + (size_t)b * NCLS * DOUT);
    float4 a0 = p[tid];
    float4 a1 = p[tid + 256];
    float s = a0.x + a0.y + a0.z + a0.w + a1.x + a1.y + a1.z + a1.w;
#pragma unroll
    for (int off = 1; off < 64; off <<= 1) s += __shfl_xor(s, off);
    __shared__ float ws[4];
    if ((tid & 63) == 0) ws[tid >> 6] = s;
    __syncthreads();
    const float inv = 1.0f / (ws[0] + ws[1] + ws[2] + ws[3]);
    a0.x *= inv; a0.y *= inv; a0.z *= inv; a0.w *= inv;
    a1.x *= inv; a1.y *= inv; a1.z *= inv; a1.w *= inv;
    p[tid]       = a0;
    p[tid + 256] = a1;
}

extern "C" void kernel_launch(void* const* d_in, const int* in_sizes, int n_in,
                              void* d_out, int out_size, void* d_ws, size_t ws_size,
                              hipStream_t stream) {
    const float* x = (const float*)d_in[0];
    const float* W = (const float*)d_in[1];
    float* out = (float*)d_out;
    hipLaunchKernelGGL(caps_kernel, dim3(NCLS * NB), dim3(BLK), 0, stream,
                       x, W, out);
    hipLaunchKernelGGL(norm_kernel, dim3(NB), dim3(256), 0, stream, out);
}